// Round 4
// baseline (3466.246 us; speedup 1.0000x reference)
//
#include <hip/hip_runtime.h>
#include <hip/hip_bf16.h>

// NRDE layer (all I/O fp32):
//   A2[a][b][c] : c<NC -> A[h*256+w] = sum_d ml_w[w,h*136+d]*logsig[b,a,1+d]
//                 c>=NC -> bias[h]   = sum_d ml_b[h*136+d]  *logsig[b,a,1+d]
//   (one MFMA GEMM, M=8192 (a*128+b), N=32896, K=136->160)
//   scan: 1 block per batch element b, 64 RK2 steps; MLP weights in REGISTERS (bf16 packed).
// times = arange => k1 of step n uses coeff idx max(n-1,0), k2 uses idx n.
//
// LAUNCH_BOUNDS LESSON (round 3): 2nd arg = min BLOCKS per CU (CUDA semantics).
// (512,2) capped VGPRs at 128 -> 160-reg weight array spilled to scratch
// (FETCH 122MB->1.04GB, WRITE 2MB->59MB, 3x slower). Use (512,1) -> 256 VGPR cap.

#define BB 128
#define SS 64
#define LL 137
#define HH 128
#define DIN 64
#define WW 256
#define DD 136
#define KP 160              // K padded for MFMA
#define NC 32768            // h*256+w columns
#define NCR 32896           // + 128 bias columns
#define AST 40              // LDS k-stride (shorts) in agemm
#define OUT2_OFF ((size_t)BB*(SS+1)*HH)

typedef __hip_bfloat16 bf16;
typedef __attribute__((ext_vector_type(8))) short short8;
typedef __attribute__((ext_vector_type(4))) float f32x4;

__device__ __forceinline__ float bf2f(bf16 x) { return __bfloat162float(x); }
__device__ __forceinline__ bf16  f2bf(float x){ return __float2bfloat16(x); }
__device__ __forceinline__ float2 upk(unsigned u){
  float2 r;
  r.x = __uint_as_float(u << 16);
  r.y = __uint_as_float(u & 0xffff0000u);
  return r;
}
__device__ __forceinline__ unsigned pk2(float a, float b){
  bf16 lo = f2bf(a), hi = f2bf(b);
  return (unsigned)*(unsigned short*)&lo | ((unsigned)*(unsigned short*)&hi << 16);
}

// ---------------- prep: coeff rows m=a*128+b (fp32 -> bf16), K padded ----------------
__global__ void prep_coeff(const float* __restrict__ logsig, bf16* __restrict__ cA){
  int m = blockIdx.x, d = threadIdx.x;
  int a = m >> 7, b = m & 127;
  float v = 0.0f;
  if (d < DD) v = logsig[(size_t)(b*SS + a)*LL + 1 + d];
  cA[(size_t)m*KP + d] = f2bf(v);
}

// ---------------- prep: btt[c][d]; c<NC: ml_w[w][h*136+d] (c=h*256+w); c>=NC: ml_b[(c-NC)*136+d] ----------------
__global__ void prep_btt(const float* __restrict__ mlw, const float* __restrict__ mlb,
                         bf16* __restrict__ btt){
  int c = blockIdx.x, d = threadIdx.x;
  float v = 0.0f;
  if (d < DD){
    if (c < NC){
      int h = c >> 8, w = c & 255;
      v = mlw[(size_t)w*(HH*DD) + h*DD + d];
    } else {
      v = mlb[(size_t)(c - NC)*DD + d];
    }
  }
  btt[(size_t)c*KP + d] = f2bf(v);
}

// ---------------- A-GEMM (round-2 proven structure): 64x128 tile, 256 thr, 4 waves ----------------
// wave w: rows (w&1)*32 (2 frags), cols (w>>1)*64 (4 frags). K = 5 chunks of 32.
// Fragment layouts (gfx950): A[m=lane&15][k=(lane>>4)*8+j]; B[k=(lane>>4)*8+j][n=lane&15];
// D[row=(lane>>4)*4+r][col=lane&15].
__global__ __launch_bounds__(256) void agemm_kernel(const bf16* __restrict__ cA,
                                                    const bf16* __restrict__ btt,
                                                    bf16* __restrict__ As, int mAbs0){
  __shared__ __align__(16) short a_sm[64*AST];
  __shared__ __align__(16) short b_sm[128*AST];
  __shared__ __align__(16) short o_sm[64*136];   // 128 cols + 8 pad
  int mt = blockIdx.x, nt = blockIdx.y;
  int t = threadIdx.x, lane = t & 63, wid = t >> 6;
  int mBlockAbs = mAbs0 + mt*64;
  int c0 = nt*128;
  int mW = (wid & 1)*32, cW = (wid >> 1)*64;

  f32x4 acc[2][4];
  for (int i = 0; i < 2; ++i)
    for (int j = 0; j < 4; ++j)
      acc[i][j] = (f32x4){0.f,0.f,0.f,0.f};

  for (int kk = 0; kk < 5; ++kk){
    int d0 = kk*32;
    { // stage A: 64 rows x 32 d = 256 x 16B
      int row = t >> 2, seg = t & 3;
      uint4 v = *(const uint4*)(cA + (size_t)(mBlockAbs+row)*KP + d0 + seg*8);
      *(uint4*)&a_sm[row*AST + seg*8] = v;
    }
    #pragma unroll
    for (int rep = 0; rep < 2; ++rep){ // stage B: 128 rows x 32 d = 512 x 16B
      int idx = t + rep*256;
      int row = idx >> 2, seg = idx & 3;
      uint4 v = *(const uint4*)(btt + (size_t)(c0+row)*KP + d0 + seg*8);
      *(uint4*)&b_sm[row*AST + seg*8] = v;
    }
    __syncthreads();
    int mr = lane & 15, q = lane >> 4;
    short8 af[2], bfr[4];
    #pragma unroll
    for (int mi = 0; mi < 2; ++mi) af[mi]  = *(const short8*)&a_sm[(mW + mi*16 + mr)*AST + q*8];
    #pragma unroll
    for (int ci = 0; ci < 4; ++ci) bfr[ci] = *(const short8*)&b_sm[(cW + ci*16 + mr)*AST + q*8];
    #pragma unroll
    for (int mi = 0; mi < 2; ++mi)
      #pragma unroll
      for (int ci = 0; ci < 4; ++ci)
        acc[mi][ci] = __builtin_amdgcn_mfma_f32_16x16x32_bf16(af[mi], bfr[ci], acc[mi][ci], 0, 0, 0);
    __syncthreads();
  }

  // epilogue: regs -> LDS bf16 -> 16B global stores
  {
    int mr = lane & 15, q = lane >> 4;
    #pragma unroll
    for (int mi = 0; mi < 2; ++mi)
      #pragma unroll
      for (int ci = 0; ci < 4; ++ci){
        int col = cW + ci*16 + mr;
        #pragma unroll
        for (int r = 0; r < 4; ++r){
          int row = mW + mi*16 + q*4 + r;
          bf16 bv = f2bf(acc[mi][ci][r]);
          o_sm[row*136 + col] = *(short*)&bv;
        }
      }
  }
  __syncthreads();
  int mLocBlock = mt*64;
  #pragma unroll
  for (int rep = 0; rep < 4; ++rep){
    int idx = t + rep*256;
    int row = idx >> 4, seg = idx & 15;
    uint4 v = *(const uint4*)&o_sm[row*136 + seg*8];
    *(uint4*)(As + (size_t)(mLocBlock + row)*NCR + c0 + seg*8) = v;
  }
}

// ---------------- scan: 1 block / batch element, 512 threads, weights in registers ----------------
__global__ __launch_bounds__(512, 1) void scan_kernel(
    const float* __restrict__ times, const float* __restrict__ initial,
    const float* __restrict__ in_w, const float* __restrict__ in_b,
    const float* __restrict__ h1_w, const float* __restrict__ h1_b,
    const float* __restrict__ h2_w, const float* __restrict__ h2_b,
    const float* __restrict__ vo_w, const float* __restrict__ vo_b,
    const bf16* __restrict__ As,
    float* __restrict__ y_state, float* __restrict__ out,
    int s0, int s1, int aBase)
{
  const int b = blockIdx.x, t = threadIdx.x;
  const int j = t & 255, half = t >> 8;          // col, K-half
  const int hh = t & 127, q4 = t >> 7;           // matvec: h, w-quarter
  __shared__ __align__(16) float yv[HH], ytmp[HH], bufA[WW], bufB[WW], kk1[HH], kk2[HH];
  __shared__ __align__(16) float part[512];

  // ---- load weights into registers (bf16 packed along K): 160 VGPRs ----
  unsigned w1p[32], w2p[64], w3p[64];
  {
    const float* w = h1_w + (size_t)(half*64)*WW + j;
    #pragma unroll
    for (int i = 0; i < 32; ++i)
      w1p[i] = pk2(w[(size_t)(2*i)*WW], w[(size_t)(2*i+1)*WW]);
  }
  {
    const float* w = h2_w + (size_t)(half*128)*WW + j;
    #pragma unroll
    for (int i = 0; i < 64; ++i)
      w2p[i] = pk2(w[(size_t)(2*i)*WW], w[(size_t)(2*i+1)*WW]);
  }
  {
    const float* w = vo_w + (size_t)(half*128)*WW + j;
    #pragma unroll
    for (int i = 0; i < 64; ++i)
      w3p[i] = pk2(w[(size_t)(2*i)*WW], w[(size_t)(2*i+1)*WW]);
  }
  const float b1 = h1_b[j], b2 = h2_b[j], b3 = vo_b[j];

  if (s0 == 0){
    if (t < HH){
      float acc = in_b[t];
      for (int i = 0; i < DIN; ++i)
        acc += initial[b*DIN + i] * in_w[(size_t)i*HH + t];
      yv[t] = acc;
      out[((size_t)b*(SS+1))*HH + t] = acc;
    }
  } else {
    if (t < HH) yv[t] = y_state[b*HH + t];
  }
  __syncthreads();

  for (int n = s0; n < s1; ++n){
    float t0 = times[n], t1 = times[n+1];
    float dt = t1 - t0;
    int idx1 = (n >= 1) ? n : 1;
    float inv1 = 1.f/(times[idx1] - times[idx1-1]);
    float inv2 = 1.f/dt;
    int a1 = ((n >= 1) ? (n-1) : 0) - aBase;
    int a2 = n - aBase;

    #pragma unroll
    for (int ev = 0; ev < 2; ++ev){
      const float* yin = (ev == 0) ? yv : ytmp;
      int aLoc = (ev == 0) ? a1 : a2;
      float inv_dtf = (ev == 0) ? inv1 : inv2;
      float* kout = (ev == 0) ? kk1 : kk2;

      // prefetch A row + bias (independent of MLP; hides HBM/L3 latency)
      uint4 Au[8];
      const bf16* Arow = As + (((size_t)aLoc*BB + b)*NCR) + hh*WW + q4*64;
      #pragma unroll
      for (int i = 0; i < 8; ++i) Au[i] = *(const uint4*)(Arow + i*8);
      float biasv = 0.f;
      if (t < HH){
        bf16 bb = As[(((size_t)aLoc*BB + b)*NCR) + NC + t];
        biasv = bf2f(bb);
      }

      // L1: 128 -> 256 relu
      {
        float acc = 0.f;
        const float4* y4 = (const float4*)(yin + half*64);
        #pragma unroll
        for (int i = 0; i < 16; ++i){
          float4 f = y4[i];
          float2 p0 = upk(w1p[2*i]), p1 = upk(w1p[2*i+1]);
          acc += f.x*p0.x + f.y*p0.y + f.z*p1.x + f.w*p1.y;
        }
        part[t] = acc;
      }
      __syncthreads();
      if (t < WW){
        float v = b1 + part[t] + part[t+256];
        bufA[t] = v > 0.f ? v : 0.f;
      }
      __syncthreads();
      // L2: 256 -> 256 relu
      {
        float acc = 0.f;
        const float4* x4 = (const float4*)(bufA + half*128);
        #pragma unroll
        for (int i = 0; i < 32; ++i){
          float4 f = x4[i];
          float2 p0 = upk(w2p[2*i]), p1 = upk(w2p[2*i+1]);
          acc += f.x*p0.x + f.y*p0.y + f.z*p1.x + f.w*p1.y;
        }
        part[t] = acc;
      }
      __syncthreads();
      if (t < WW){
        float v = b2 + part[t] + part[t+256];
        bufB[t] = v > 0.f ? v : 0.f;
      }
      __syncthreads();
      // L3: 256 -> 256 tanh
      {
        float acc = 0.f;
        const float4* x4 = (const float4*)(bufB + half*128);
        #pragma unroll
        for (int i = 0; i < 32; ++i){
          float4 f = x4[i];
          float2 p0 = upk(w3p[2*i]), p1 = upk(w3p[2*i+1]);
          acc += f.x*p0.x + f.y*p0.y + f.z*p1.x + f.w*p1.y;
        }
        part[t] = acc;
      }
      __syncthreads();
      if (t < WW){
        float v = b3 + part[t] + part[t+256];
        bufA[t] = tanhf(v);
      }
      __syncthreads();
      // matvec: k[h] = (sum_w h3[w]*A[h][w] + bias)/dtf
      {
        const float* hv = bufA + q4*64;
        float s = 0.f;
        #pragma unroll
        for (int w8 = 0; w8 < 8; ++w8){
          uint4 u = Au[w8];
          float2 p;
          p = upk(u.x); s += hv[w8*8+0]*p.x + hv[w8*8+1]*p.y;
          p = upk(u.y); s += hv[w8*8+2]*p.x + hv[w8*8+3]*p.y;
          p = upk(u.z); s += hv[w8*8+4]*p.x + hv[w8*8+5]*p.y;
          p = upk(u.w); s += hv[w8*8+6]*p.x + hv[w8*8+7]*p.y;
        }
        part[t] = s;
      }
      __syncthreads();
      if (t < HH)
        kout[t] = (part[t] + part[t+128] + part[t+256] + part[t+384] + biasv) * inv_dtf;
      __syncthreads();
      if (ev == 0){
        if (t < HH) ytmp[t] = yv[t] + dt*kk1[t];
        __syncthreads();
      }
    }

    if (t < HH){
      float ynew = yv[t] + 0.5f*dt*(kk1[t] + kk2[t]);
      yv[t] = ynew;
      out[((size_t)b*(SS+1) + (n+1))*HH + t] = ynew;
    }
    __syncthreads();
  }

  if (t < HH){
    y_state[b*HH + t] = yv[t];
    if (s1 == SS) out[OUT2_OFF + (size_t)b*HH + t] = yv[t];
  }
}

extern "C" void kernel_launch(void* const* d_in, const int* in_sizes, int n_in,
                              void* d_out, int out_size, void* d_ws, size_t ws_size,
                              hipStream_t stream)
{
  (void)in_sizes; (void)n_in; (void)out_size;
  const float* times   = (const float*)d_in[0];
  const float* logsig  = (const float*)d_in[1];
  const float* initial = (const float*)d_in[2];
  const float* in_w    = (const float*)d_in[3];
  const float* in_b    = (const float*)d_in[4];
  const float* h1_w    = (const float*)d_in[5];
  const float* h1_b    = (const float*)d_in[6];
  const float* h2_w    = (const float*)d_in[7];
  const float* h2_b    = (const float*)d_in[8];
  const float* vo_w    = (const float*)d_in[9];
  const float* vo_b    = (const float*)d_in[10];
  const float* ml_w    = (const float*)d_in[11];
  const float* ml_b    = (const float*)d_in[12];
  float* out = (float*)d_out;

  char* ws = (char*)d_ws;
  size_t off = 0;
  bf16* cA      = (bf16*)(ws + off); off += (size_t)8192*KP*2;        // 2.62 MB
  bf16* btt     = (bf16*)(ws + off); off += (size_t)NCR*KP*2;         // 10.53 MB
  float* y_state= (float*)(ws + off); off += (size_t)BB*HH*4;         // 64 KB
  bf16* As      = (bf16*)(ws + off);
  size_t perA = (size_t)BB*NCR*2;                                     // 8.42 MB per a-index
  size_t avail = (ws_size > off) ? (ws_size - off) : 0;
  int C = (int)(avail / perA);
  if (C > SS) C = SS;
  if (C < 2) return;

  prep_coeff<<<8192, 160, 0, stream>>>(logsig, cA);
  prep_btt<<<NCR, 160, 0, stream>>>(ml_w, ml_b, btt);

  int s = 0, aB = 0;
  while (s < SS){
    int cc = SS - aB; if (cc > C) cc = C;
    agemm_kernel<<<dim3(cc*2, 257), 256, 0, stream>>>(cA, btt, As, aB*BB);
    int sEnd = aB + cc; if (sEnd > SS) sEnd = SS;
    scan_kernel<<<BB, 512, 0, stream>>>(times, initial, in_w, in_b, h1_w, h1_b,
        h2_w, h2_b, vo_w, vo_b, As, y_state, out, s, sEnd, aB);
    s = sEnd;
    aB = sEnd - 1;
  }
}

// Round 5
// 3443.674 us; speedup vs baseline: 1.0066x; 1.0066x over previous
//
#include <hip/hip_runtime.h>
#include <hip/hip_bf16.h>

// NRDE layer (all I/O fp32):
//   A2[a][b][c] : c<NC -> A[h*256+w] = sum_d ml_w[w,h*136+d]*logsig[b,a,1+d]
//                 c>=NC -> bias[h]   = sum_d ml_b[h*136+d]  *logsig[b,a,1+d]
//   (one MFMA GEMM, M=8192 (a*128+b), N=32896, K=136->160)
//   scan: 1 block per batch element b, 64 RK2 steps; MLP weights in REGISTERS.
// times = arange => k1 of step n uses coeff idx max(n-1,0), k2 uses idx n.
//
// SPILL LESSON (rounds 3/4): local ARRAYS (unsigned w[64], uint4 Au[8]) are allocas;
// SROA runs before unrolling -> not promoted -> amdgpu-promote-alloca size limit ->
// SCRATCH (VGPR stuck at 128, FETCH 1 GB of reloads). Fix: ext_vector_type values
// and named uint4s -- SSA, never allocas.

#define BB 128
#define SS 64
#define LL 137
#define HH 128
#define DIN 64
#define WW 256
#define DD 136
#define KP 160              // K padded for MFMA
#define NC 32768            // h*256+w columns
#define NCR 32896           // + 128 bias columns
#define AST 40              // LDS k-stride (shorts) in agemm
#define OUT2_OFF ((size_t)BB*(SS+1)*HH)

typedef __hip_bfloat16 bf16;
typedef __attribute__((ext_vector_type(8))) short short8;
typedef __attribute__((ext_vector_type(4))) float f32x4;
typedef __attribute__((ext_vector_type(16))) unsigned uint16v;

__device__ __forceinline__ float bf2f(bf16 x) { return __bfloat162float(x); }
__device__ __forceinline__ bf16  f2bf(float x){ return __float2bfloat16(x); }
__device__ __forceinline__ float2 upk(unsigned u){
  float2 r;
  r.x = __uint_as_float(u << 16);
  r.y = __uint_as_float(u & 0xffff0000u);
  return r;
}
__device__ __forceinline__ unsigned pk2(float a, float b){
  bf16 lo = f2bf(a), hi = f2bf(b);
  return (unsigned)*(unsigned short*)&lo | ((unsigned)*(unsigned short*)&hi << 16);
}

// ---------------- prep: coeff rows m=a*128+b (fp32 -> bf16), K padded ----------------
__global__ void prep_coeff(const float* __restrict__ logsig, bf16* __restrict__ cA){
  int m = blockIdx.x, d = threadIdx.x;
  int a = m >> 7, b = m & 127;
  float v = 0.0f;
  if (d < DD) v = logsig[(size_t)(b*SS + a)*LL + 1 + d];
  cA[(size_t)m*KP + d] = f2bf(v);
}

// ---------------- prep: btt[c][d]; c<NC: ml_w[w][h*136+d] (c=h*256+w); c>=NC: ml_b[(c-NC)*136+d] ----------------
__global__ void prep_btt(const float* __restrict__ mlw, const float* __restrict__ mlb,
                         bf16* __restrict__ btt){
  int c = blockIdx.x, d = threadIdx.x;
  float v = 0.0f;
  if (d < DD){
    if (c < NC){
      int h = c >> 8, w = c & 255;
      v = mlw[(size_t)w*(HH*DD) + h*DD + d];
    } else {
      v = mlb[(size_t)(c - NC)*DD + d];
    }
  }
  btt[(size_t)c*KP + d] = f2bf(v);
}

// ---------------- A-GEMM: 64x128 tile, 256 thr, 4 waves (proven structure) ----------------
__global__ __launch_bounds__(256) void agemm_kernel(const bf16* __restrict__ cA,
                                                    const bf16* __restrict__ btt,
                                                    bf16* __restrict__ As, int mAbs0){
  __shared__ __align__(16) short a_sm[64*AST];
  __shared__ __align__(16) short b_sm[128*AST];
  __shared__ __align__(16) short o_sm[64*136];
  int mt = blockIdx.x, nt = blockIdx.y;
  int t = threadIdx.x, lane = t & 63, wid = t >> 6;
  int mBlockAbs = mAbs0 + mt*64;
  int c0 = nt*128;
  int mW = (wid & 1)*32, cW = (wid >> 1)*64;

  f32x4 acc[2][4];
  for (int i = 0; i < 2; ++i)
    for (int j = 0; j < 4; ++j)
      acc[i][j] = (f32x4){0.f,0.f,0.f,0.f};

  for (int kk = 0; kk < 5; ++kk){
    int d0 = kk*32;
    {
      int row = t >> 2, seg = t & 3;
      uint4 v = *(const uint4*)(cA + (size_t)(mBlockAbs+row)*KP + d0 + seg*8);
      *(uint4*)&a_sm[row*AST + seg*8] = v;
    }
    #pragma unroll
    for (int rep = 0; rep < 2; ++rep){
      int idx = t + rep*256;
      int row = idx >> 2, seg = idx & 3;
      uint4 v = *(const uint4*)(btt + (size_t)(c0+row)*KP + d0 + seg*8);
      *(uint4*)&b_sm[row*AST + seg*8] = v;
    }
    __syncthreads();
    int mr = lane & 15, q = lane >> 4;
    short8 af0 = *(const short8*)&a_sm[(mW + mr)*AST + q*8];
    short8 af1 = *(const short8*)&a_sm[(mW + 16 + mr)*AST + q*8];
    #pragma unroll
    for (int ci = 0; ci < 4; ++ci){
      short8 bfr = *(const short8*)&b_sm[(cW + ci*16 + mr)*AST + q*8];
      acc[0][ci] = __builtin_amdgcn_mfma_f32_16x16x32_bf16(af0, bfr, acc[0][ci], 0, 0, 0);
      acc[1][ci] = __builtin_amdgcn_mfma_f32_16x16x32_bf16(af1, bfr, acc[1][ci], 0, 0, 0);
    }
    __syncthreads();
  }

  {
    int mr = lane & 15, q = lane >> 4;
    #pragma unroll
    for (int mi = 0; mi < 2; ++mi)
      #pragma unroll
      for (int ci = 0; ci < 4; ++ci){
        int col = cW + ci*16 + mr;
        #pragma unroll
        for (int r = 0; r < 4; ++r){
          int row = mW + mi*16 + q*4 + r;
          bf16 bv = f2bf(acc[mi][ci][r]);
          o_sm[row*136 + col] = *(short*)&bv;
        }
      }
  }
  __syncthreads();
  int mLocBlock = mt*64;
  #pragma unroll
  for (int rep = 0; rep < 4; ++rep){
    int idx = t + rep*256;
    int row = idx >> 4, seg = idx & 15;
    uint4 v = *(const uint4*)&o_sm[row*136 + seg*8];
    *(uint4*)(As + (size_t)(mLocBlock + row)*NCR + c0 + seg*8) = v;
  }
}

// ---------------- scan: 1 block / batch element, 512 threads, weights in SSA vector regs ----------------
// MLPV: 8 float4 of input against one uint16v of packed-bf16 weights (16 pairs).
#define MLPV(vec, xbase) \
  { _Pragma("unroll") \
    for (int i = 0; i < 8; ++i){ \
      float4 f = x4[(xbase) + i]; \
      float2 p0 = upk(vec[2*i]), p1 = upk(vec[2*i+1]); \
      acc += f.x*p0.x + f.y*p0.y + f.z*p1.x + f.w*p1.y; \
    } }
#define AMAC(u, o) { float2 p; \
  p = upk(u.x); s += hv[(o)+0]*p.x + hv[(o)+1]*p.y; \
  p = upk(u.y); s += hv[(o)+2]*p.x + hv[(o)+3]*p.y; \
  p = upk(u.z); s += hv[(o)+4]*p.x + hv[(o)+5]*p.y; \
  p = upk(u.w); s += hv[(o)+6]*p.x + hv[(o)+7]*p.y; }

__global__ __launch_bounds__(512, 1) void scan_kernel(
    const float* __restrict__ times, const float* __restrict__ initial,
    const float* __restrict__ in_w, const float* __restrict__ in_b,
    const float* __restrict__ h1_w, const float* __restrict__ h1_b,
    const float* __restrict__ h2_w, const float* __restrict__ h2_b,
    const float* __restrict__ vo_w, const float* __restrict__ vo_b,
    const bf16* __restrict__ As,
    float* __restrict__ y_state, float* __restrict__ out,
    int s0, int s1, int aBase)
{
  const int b = blockIdx.x, t = threadIdx.x;
  const int j = t & 255, half = t >> 8;          // col, K-half
  const int hh = t & 127, q4 = t >> 7;           // matvec: h, w-quarter
  __shared__ __align__(16) float yv[HH], ytmp[HH], bufA[WW], bufB[WW], kk1[HH], kk2[HH];
  __shared__ __align__(16) float part[512];

  // ---- weights as SSA vectors (10 x uint16v = 160 VGPRs) ----
  uint16v w1a, w1b, w2a, w2b, w2c, w2d, w3a, w3b, w3c, w3d;
  {
    const float* w = h1_w + (size_t)(half*64)*WW + j;
    #pragma unroll
    for (int i = 0; i < 16; ++i) w1a[i] = pk2(w[(size_t)(2*i)*WW],    w[(size_t)(2*i+1)*WW]);
    #pragma unroll
    for (int i = 0; i < 16; ++i) w1b[i] = pk2(w[(size_t)(32+2*i)*WW], w[(size_t)(33+2*i)*WW]);
  }
  {
    const float* w = h2_w + (size_t)(half*128)*WW + j;
    #pragma unroll
    for (int i = 0; i < 16; ++i) w2a[i] = pk2(w[(size_t)(2*i)*WW],    w[(size_t)(2*i+1)*WW]);
    #pragma unroll
    for (int i = 0; i < 16; ++i) w2b[i] = pk2(w[(size_t)(32+2*i)*WW], w[(size_t)(33+2*i)*WW]);
    #pragma unroll
    for (int i = 0; i < 16; ++i) w2c[i] = pk2(w[(size_t)(64+2*i)*WW], w[(size_t)(65+2*i)*WW]);
    #pragma unroll
    for (int i = 0; i < 16; ++i) w2d[i] = pk2(w[(size_t)(96+2*i)*WW], w[(size_t)(97+2*i)*WW]);
  }
  {
    const float* w = vo_w + (size_t)(half*128)*WW + j;
    #pragma unroll
    for (int i = 0; i < 16; ++i) w3a[i] = pk2(w[(size_t)(2*i)*WW],    w[(size_t)(2*i+1)*WW]);
    #pragma unroll
    for (int i = 0; i < 16; ++i) w3b[i] = pk2(w[(size_t)(32+2*i)*WW], w[(size_t)(33+2*i)*WW]);
    #pragma unroll
    for (int i = 0; i < 16; ++i) w3c[i] = pk2(w[(size_t)(64+2*i)*WW], w[(size_t)(65+2*i)*WW]);
    #pragma unroll
    for (int i = 0; i < 16; ++i) w3d[i] = pk2(w[(size_t)(96+2*i)*WW], w[(size_t)(97+2*i)*WW]);
  }
  const float b1 = h1_b[j], b2 = h2_b[j], b3 = vo_b[j];

  if (s0 == 0){
    if (t < HH){
      float acc = in_b[t];
      for (int i = 0; i < DIN; ++i)
        acc += initial[b*DIN + i] * in_w[(size_t)i*HH + t];
      yv[t] = acc;
      out[((size_t)b*(SS+1))*HH + t] = acc;
    }
  } else {
    if (t < HH) yv[t] = y_state[b*HH + t];
  }
  __syncthreads();

  for (int n = s0; n < s1; ++n){
    float t0 = times[n], t1 = times[n+1];
    float dt = t1 - t0;
    int idx1 = (n >= 1) ? n : 1;
    float inv1 = 1.f/(times[idx1] - times[idx1-1]);
    float inv2 = 1.f/dt;
    int a1 = ((n >= 1) ? (n-1) : 0) - aBase;
    int a2 = n - aBase;

    #pragma unroll
    for (int ev = 0; ev < 2; ++ev){
      const float* yin = (ev == 0) ? yv : ytmp;
      int aLoc = (ev == 0) ? a1 : a2;
      float inv_dtf = (ev == 0) ? inv1 : inv2;
      float* kout = (ev == 0) ? kk1 : kk2;

      // prefetch A row + bias as named SSA values (issued before the MLP)
      const bf16* Arow = As + (((size_t)aLoc*BB + b)*NCR) + hh*WW + q4*64;
      uint4 u0 = *(const uint4*)(Arow +  0);
      uint4 u1 = *(const uint4*)(Arow +  8);
      uint4 u2 = *(const uint4*)(Arow + 16);
      uint4 u3 = *(const uint4*)(Arow + 24);
      uint4 u4 = *(const uint4*)(Arow + 32);
      uint4 u5 = *(const uint4*)(Arow + 40);
      uint4 u6 = *(const uint4*)(Arow + 48);
      uint4 u7 = *(const uint4*)(Arow + 56);
      float biasv = 0.f;
      if (t < HH) biasv = bf2f(As[(((size_t)aLoc*BB + b)*NCR) + NC + t]);

      // L1: 128 -> 256 relu (K-half = 64 rows/thread)
      {
        float acc = 0.f;
        const float4* x4 = (const float4*)(yin + half*64);
        MLPV(w1a, 0)
        MLPV(w1b, 8)
        part[t] = acc;
      }
      __syncthreads();
      if (t < WW){
        float v = b1 + part[t] + part[t+256];
        bufA[t] = v > 0.f ? v : 0.f;
      }
      __syncthreads();
      // L2: 256 -> 256 relu (K-half = 128 rows/thread)
      {
        float acc = 0.f;
        const float4* x4 = (const float4*)(bufA + half*128);
        MLPV(w2a, 0)
        MLPV(w2b, 8)
        MLPV(w2c, 16)
        MLPV(w2d, 24)
        part[t] = acc;
      }
      __syncthreads();
      if (t < WW){
        float v = b2 + part[t] + part[t+256];
        bufB[t] = v > 0.f ? v : 0.f;
      }
      __syncthreads();
      // L3: 256 -> 256 tanh
      {
        float acc = 0.f;
        const float4* x4 = (const float4*)(bufB + half*128);
        MLPV(w3a, 0)
        MLPV(w3b, 8)
        MLPV(w3c, 16)
        MLPV(w3d, 24)
        part[t] = acc;
      }
      __syncthreads();
      if (t < WW){
        float v = b3 + part[t] + part[t+256];
        bufA[t] = tanhf(v);
      }
      __syncthreads();
      // matvec: k[h] = (sum_w h3[w]*A[h][w] + bias)/dtf
      {
        const float* hv = bufA + q4*64;
        float s = 0.f;
        AMAC(u0,  0) AMAC(u1,  8) AMAC(u2, 16) AMAC(u3, 24)
        AMAC(u4, 32) AMAC(u5, 40) AMAC(u6, 48) AMAC(u7, 56)
        part[t] = s;
      }
      __syncthreads();
      if (t < HH)
        kout[t] = (part[t] + part[t+128] + part[t+256] + part[t+384] + biasv) * inv_dtf;
      __syncthreads();
      if (ev == 0){
        if (t < HH) ytmp[t] = yv[t] + dt*kk1[t];
        __syncthreads();
      }
    }

    if (t < HH){
      float ynew = yv[t] + 0.5f*dt*(kk1[t] + kk2[t]);
      yv[t] = ynew;
      out[((size_t)b*(SS+1) + (n+1))*HH + t] = ynew;
    }
    __syncthreads();
  }

  if (t < HH){
    y_state[b*HH + t] = yv[t];
    if (s1 == SS) out[OUT2_OFF + (size_t)b*HH + t] = yv[t];
  }
}

extern "C" void kernel_launch(void* const* d_in, const int* in_sizes, int n_in,
                              void* d_out, int out_size, void* d_ws, size_t ws_size,
                              hipStream_t stream)
{
  (void)in_sizes; (void)n_in; (void)out_size;
  const float* times   = (const float*)d_in[0];
  const float* logsig  = (const float*)d_in[1];
  const float* initial = (const float*)d_in[2];
  const float* in_w    = (const float*)d_in[3];
  const float* in_b    = (const float*)d_in[4];
  const float* h1_w    = (const float*)d_in[5];
  const float* h1_b    = (const float*)d_in[6];
  const float* h2_w    = (const float*)d_in[7];
  const float* h2_b    = (const float*)d_in[8];
  const float* vo_w    = (const float*)d_in[9];
  const float* vo_b    = (const float*)d_in[10];
  const float* ml_w    = (const float*)d_in[11];
  const float* ml_b    = (const float*)d_in[12];
  float* out = (float*)d_out;

  char* ws = (char*)d_ws;
  size_t off = 0;
  bf16* cA      = (bf16*)(ws + off); off += (size_t)8192*KP*2;        // 2.62 MB
  bf16* btt     = (bf16*)(ws + off); off += (size_t)NCR*KP*2;         // 10.53 MB
  float* y_state= (float*)(ws + off); off += (size_t)BB*HH*4;         // 64 KB
  bf16* As      = (bf16*)(ws + off);
  size_t perA = (size_t)BB*NCR*2;                                     // 8.42 MB per a-index
  size_t avail = (ws_size > off) ? (ws_size - off) : 0;
  int C = (int)(avail / perA);
  if (C > SS) C = SS;
  if (C < 2) return;

  prep_coeff<<<8192, 160, 0, stream>>>(logsig, cA);
  prep_btt<<<NCR, 160, 0, stream>>>(ml_w, ml_b, btt);

  int s = 0, aB = 0;
  while (s < SS){
    int cc = SS - aB; if (cc > C) cc = C;
    agemm_kernel<<<dim3(cc*2, 257), 256, 0, stream>>>(cA, btt, As, aB*BB);
    int sEnd = aB + cc; if (sEnd > SS) sEnd = SS;
    scan_kernel<<<BB, 512, 0, stream>>>(times, initial, in_w, in_b, h1_w, h1_b,
        h2_w, h2_b, vo_w, vo_b, As, y_state, out, s, sEnd, aB);
    s = sEnd;
    aB = sEnd - 1;
  }
}

// Round 6
// 3035.992 us; speedup vs baseline: 1.1417x; 1.1343x over previous
//
#include <hip/hip_runtime.h>
#include <hip/hip_bf16.h>

// NRDE layer (all I/O fp32):
//   A2[a][b][c] : c<NC -> A[h*256+w] = sum_d ml_w[w,h*136+d]*logsig[b,a,1+d]
//                 c>=NC -> bias[h]   = sum_d ml_b[h*136+d]  *logsig[b,a,1+d]
//   (MFMA GEMM, M=8192 (a*128+b), N=32896, K=136->160)
//   scan: 1 block (1024 thr) per batch element, 64 RK2 steps; MLP weights STREAMED
//   from L2 as pre-packed bf16 (shared across all 128 blocks -> L2 broadcast).
//
// LESSON (r3-r5): per-thread register-resident weights are unwinnable -- the AMDGPU
// backend caps 512-thr kernels at 128 VGPR for occupancy and spills to scratch
// (private, un-shareable, L2-thrashing). Round-2's shared-L2 streaming was 2.5x
// faster end-to-end. This round: streaming, but bf16-packed (half bytes), 1024 thr.

#define BB 128
#define SS 64
#define LL 137
#define HH 128
#define DIN 64
#define WW 256
#define DD 136
#define KP 160              // K padded for MFMA
#define NC 32768            // h*256+w columns
#define NCR 32896           // + 128 bias columns
#define AST 40              // LDS k-stride (shorts) in agemm
#define OUT2_OFF ((size_t)BB*(SS+1)*HH)

typedef __hip_bfloat16 bf16;
typedef __attribute__((ext_vector_type(8))) short short8;
typedef __attribute__((ext_vector_type(4))) float f32x4;

__device__ __forceinline__ float bf2f(bf16 x) { return __bfloat162float(x); }
__device__ __forceinline__ bf16  f2bf(float x){ return __float2bfloat16(x); }
__device__ __forceinline__ float2 upk(unsigned u){
  float2 r;
  r.x = __uint_as_float(u << 16);
  r.y = __uint_as_float(u & 0xffff0000u);
  return r;
}
__device__ __forceinline__ unsigned pk2(float a, float b){
  bf16 lo = f2bf(a), hi = f2bf(b);
  return (unsigned)*(unsigned short*)&lo | ((unsigned)*(unsigned short*)&hi << 16);
}
// inline tanh via v_exp + v_rcp (avoid any ocml call)
__device__ __forceinline__ float tanh_fast(float v){
  float vc = fminf(fmaxf(v, -9.f), 9.f);
  float e = __expf(2.f*vc);
  return (e - 1.f) * __builtin_amdgcn_rcpf(e + 1.f);
}

// ---------------- prep: coeff rows m=a*128+b (fp32 -> bf16), K padded ----------------
__global__ void prep_coeff(const float* __restrict__ logsig, bf16* __restrict__ cA){
  int m = blockIdx.x, d = threadIdx.x;
  int a = m >> 7, b = m & 127;
  float v = 0.0f;
  if (d < DD) v = logsig[(size_t)(b*SS + a)*LL + 1 + d];
  cA[(size_t)m*KP + d] = f2bf(v);
}

// ---------------- prep: btt[c][d]; c<NC: ml_w[w][h*136+d] (c=h*256+w); c>=NC: ml_b ----------------
__global__ void prep_btt(const float* __restrict__ mlw, const float* __restrict__ mlb,
                         bf16* __restrict__ btt){
  int c = blockIdx.x, d = threadIdx.x;
  float v = 0.0f;
  if (d < DD){
    if (c < NC){
      int h = c >> 8, w = c & 255;
      v = mlw[(size_t)w*(HH*DD) + h*DD + d];
    } else {
      v = mlb[(size_t)(c - NC)*DD + d];
    }
  }
  btt[(size_t)c*KP + d] = f2bf(v);
}

// ---------------- prep: pack MLP weights as bf16-pair quads, layout [k/4][j] uint2 ----------------
// w1q: 32 rows (K=128), w2q/w3q: 64 rows (K=256); each row = 256 uint2 (col j).
__global__ void prep_wpack(const float* __restrict__ h1w, const float* __restrict__ h2w,
                           const float* __restrict__ vow,
                           uint2* __restrict__ w1q, uint2* __restrict__ w2q,
                           uint2* __restrict__ w3q){
  int idx = blockIdx.x*256 + threadIdx.x;   // 0..40959
  int j = idx & 255, q = idx >> 8;          // q 0..159
  if (q < 32){
    int k = q*4;
    w1q[q*256 + j] = make_uint2(
      pk2(h1w[(size_t)k*WW + j],     h1w[(size_t)(k+1)*WW + j]),
      pk2(h1w[(size_t)(k+2)*WW + j], h1w[(size_t)(k+3)*WW + j]));
  } else if (q < 96){
    int q2 = q - 32, k = q2*4;
    w2q[q2*256 + j] = make_uint2(
      pk2(h2w[(size_t)k*WW + j],     h2w[(size_t)(k+1)*WW + j]),
      pk2(h2w[(size_t)(k+2)*WW + j], h2w[(size_t)(k+3)*WW + j]));
  } else {
    int q3 = q - 96, k = q3*4;
    w3q[q3*256 + j] = make_uint2(
      pk2(vow[(size_t)k*WW + j],     vow[(size_t)(k+1)*WW + j]),
      pk2(vow[(size_t)(k+2)*WW + j], vow[(size_t)(k+3)*WW + j]));
  }
}

// ---------------- A-GEMM: 64x128 tile, 256 thr, 4 waves (proven structure) ----------------
__global__ __launch_bounds__(256) void agemm_kernel(const bf16* __restrict__ cA,
                                                    const bf16* __restrict__ btt,
                                                    bf16* __restrict__ As, int mAbs0){
  __shared__ __align__(16) short a_sm[64*AST];
  __shared__ __align__(16) short b_sm[128*AST];
  __shared__ __align__(16) short o_sm[64*136];
  int mt = blockIdx.x, nt = blockIdx.y;
  int t = threadIdx.x, lane = t & 63, wid = t >> 6;
  int mBlockAbs = mAbs0 + mt*64;
  int c0 = nt*128;
  int mW = (wid & 1)*32, cW = (wid >> 1)*64;

  f32x4 acc[2][4];
  for (int i = 0; i < 2; ++i)
    for (int j = 0; j < 4; ++j)
      acc[i][j] = (f32x4){0.f,0.f,0.f,0.f};

  for (int kk = 0; kk < 5; ++kk){
    int d0 = kk*32;
    {
      int row = t >> 2, seg = t & 3;
      uint4 v = *(const uint4*)(cA + (size_t)(mBlockAbs+row)*KP + d0 + seg*8);
      *(uint4*)&a_sm[row*AST + seg*8] = v;
    }
    #pragma unroll
    for (int rep = 0; rep < 2; ++rep){
      int idx = t + rep*256;
      int row = idx >> 2, seg = idx & 3;
      uint4 v = *(const uint4*)(btt + (size_t)(c0+row)*KP + d0 + seg*8);
      *(uint4*)&b_sm[row*AST + seg*8] = v;
    }
    __syncthreads();
    int mr = lane & 15, q = lane >> 4;
    short8 af0 = *(const short8*)&a_sm[(mW + mr)*AST + q*8];
    short8 af1 = *(const short8*)&a_sm[(mW + 16 + mr)*AST + q*8];
    #pragma unroll
    for (int ci = 0; ci < 4; ++ci){
      short8 bfr = *(const short8*)&b_sm[(cW + ci*16 + mr)*AST + q*8];
      acc[0][ci] = __builtin_amdgcn_mfma_f32_16x16x32_bf16(af0, bfr, acc[0][ci], 0, 0, 0);
      acc[1][ci] = __builtin_amdgcn_mfma_f32_16x16x32_bf16(af1, bfr, acc[1][ci], 0, 0, 0);
    }
    __syncthreads();
  }

  {
    int mr = lane & 15, q = lane >> 4;
    #pragma unroll
    for (int mi = 0; mi < 2; ++mi)
      #pragma unroll
      for (int ci = 0; ci < 4; ++ci){
        int col = cW + ci*16 + mr;
        #pragma unroll
        for (int r = 0; r < 4; ++r){
          int row = mW + mi*16 + q*4 + r;
          bf16 bv = f2bf(acc[mi][ci][r]);
          o_sm[row*136 + col] = *(short*)&bv;
        }
      }
  }
  __syncthreads();
  int mLocBlock = mt*64;
  #pragma unroll
  for (int rep = 0; rep < 4; ++rep){
    int idx = t + rep*256;
    int row = idx >> 4, seg = idx & 15;
    uint4 v = *(const uint4*)&o_sm[row*136 + seg*8];
    *(uint4*)(As + (size_t)(mLocBlock + row)*NCR + c0 + seg*8) = v;
  }
}

// ---------------- scan: 1 block / batch element, 1024 threads (16 waves) ----------------
// MLP: thread (j = t&255, kq = t>>8) handles output col j, K-quarter kq.
// Matvec: thread (h = t&127, e8 = t>>7) handles row h, w-eighth e8.
#define AMAC(u, o) { float2 p; \
  p = upk(u.x); s += hv[(o)+0]*p.x + hv[(o)+1]*p.y; \
  p = upk(u.y); s += hv[(o)+2]*p.x + hv[(o)+3]*p.y; \
  p = upk(u.z); s += hv[(o)+4]*p.x + hv[(o)+5]*p.y; \
  p = upk(u.w); s += hv[(o)+6]*p.x + hv[(o)+7]*p.y; }

__global__ __launch_bounds__(1024) void scan_kernel(
    const float* __restrict__ times, const float* __restrict__ initial,
    const float* __restrict__ in_w, const float* __restrict__ in_b,
    const float* __restrict__ h1_b, const float* __restrict__ h2_b,
    const float* __restrict__ vo_b,
    const uint2* __restrict__ w1q, const uint2* __restrict__ w2q,
    const uint2* __restrict__ w3q,
    const bf16* __restrict__ As,
    float* __restrict__ y_state, float* __restrict__ out,
    int s0, int s1, int aBase)
{
  const int b = blockIdx.x, t = threadIdx.x;
  const int j = t & 255, kq = t >> 8;      // MLP mapping
  const int hh = t & 127, e8 = t >> 7;     // matvec mapping
  __shared__ __align__(16) float yv[HH], ytmp[HH], bufA[WW], bufB[WW], kk1[HH], kk2[HH];
  __shared__ __align__(16) float part[1024];

  const float b1 = h1_b[j], b2 = h2_b[j], b3 = vo_b[j];

  if (s0 == 0){
    if (t < HH){
      float acc = in_b[t];
      for (int i = 0; i < DIN; ++i)
        acc += initial[b*DIN + i] * in_w[(size_t)i*HH + t];
      yv[t] = acc;
      out[((size_t)b*(SS+1))*HH + t] = acc;
    }
  } else {
    if (t < HH) yv[t] = y_state[b*HH + t];
  }
  __syncthreads();

  for (int n = s0; n < s1; ++n){
    float t0 = times[n], t1 = times[n+1];
    float dt = t1 - t0;
    int idx1 = (n >= 1) ? n : 1;
    float inv1 = 1.f/(times[idx1] - times[idx1-1]);
    float inv2 = 1.f/dt;
    int a1 = ((n >= 1) ? (n-1) : 0) - aBase;
    int a2 = n - aBase;

    #pragma unroll 1
    for (int ev = 0; ev < 2; ++ev){
      const float* yin = (ev == 0) ? yv : ytmp;
      int aLoc = (ev == 0) ? a1 : a2;
      float inv_dtf = (ev == 0) ? inv1 : inv2;
      float* kout = (ev == 0) ? kk1 : kk2;

      // prefetch A slice + bias early (overlaps the MLP)
      const bf16* Arow = As + ((size_t)aLoc*BB + b)*NCR + hh*WW + e8*32;
      uint4 u0 = *(const uint4*)(Arow +  0);
      uint4 u1 = *(const uint4*)(Arow +  8);
      uint4 u2 = *(const uint4*)(Arow + 16);
      uint4 u3 = *(const uint4*)(Arow + 24);
      float biasv = (t < HH) ? bf2f(As[((size_t)aLoc*BB + b)*NCR + NC + t]) : 0.f;

      // L1: 128 -> 256 relu (K-quarter = 32 rows/thread)
      {
        float acc = 0.f;
        const float4* x4 = (const float4*)(yin + kq*32);
        const uint2* wp = w1q + (size_t)(kq*8)*256 + j;
        #pragma unroll
        for (int i = 0; i < 8; ++i){
          uint2 u = wp[(size_t)i*256];
          float4 f = x4[i];
          float2 p0 = upk(u.x), p1 = upk(u.y);
          acc += f.x*p0.x + f.y*p0.y + f.z*p1.x + f.w*p1.y;
        }
        part[t] = acc;
      }
      __syncthreads();
      if (t < WW){
        float v = b1 + part[t] + part[t+256] + part[t+512] + part[t+768];
        bufA[t] = v > 0.f ? v : 0.f;
      }
      __syncthreads();
      // L2: 256 -> 256 relu (K-quarter = 64 rows/thread)
      {
        float acc = 0.f;
        const float4* x4 = (const float4*)(bufA + kq*64);
        const uint2* wp = w2q + (size_t)(kq*16)*256 + j;
        #pragma unroll
        for (int i = 0; i < 16; ++i){
          uint2 u = wp[(size_t)i*256];
          float4 f = x4[i];
          float2 p0 = upk(u.x), p1 = upk(u.y);
          acc += f.x*p0.x + f.y*p0.y + f.z*p1.x + f.w*p1.y;
        }
        part[t] = acc;
      }
      __syncthreads();
      if (t < WW){
        float v = b2 + part[t] + part[t+256] + part[t+512] + part[t+768];
        bufB[t] = v > 0.f ? v : 0.f;
      }
      __syncthreads();
      // L3: 256 -> 256 tanh
      {
        float acc = 0.f;
        const float4* x4 = (const float4*)(bufB + kq*64);
        const uint2* wp = w3q + (size_t)(kq*16)*256 + j;
        #pragma unroll
        for (int i = 0; i < 16; ++i){
          uint2 u = wp[(size_t)i*256];
          float4 f = x4[i];
          float2 p0 = upk(u.x), p1 = upk(u.y);
          acc += f.x*p0.x + f.y*p0.y + f.z*p1.x + f.w*p1.y;
        }
        part[t] = acc;
      }
      __syncthreads();
      if (t < WW){
        float v = b3 + part[t] + part[t+256] + part[t+512] + part[t+768];
        bufA[t] = tanh_fast(v);
      }
      __syncthreads();
      // matvec: k[h] = (sum_w h3[w]*A[h][w] + bias)/dtf  (w-eighth = 32 per thread)
      {
        const float* hv = bufA + e8*32;
        float s = 0.f;
        AMAC(u0, 0) AMAC(u1, 8) AMAC(u2, 16) AMAC(u3, 24)
        part[t] = s;
      }
      __syncthreads();
      if (t < HH)
        kout[t] = (part[t] + part[t+128] + part[t+256] + part[t+384]
                 + part[t+512] + part[t+640] + part[t+768] + part[t+896] + biasv) * inv_dtf;
      __syncthreads();
      if (ev == 0){
        if (t < HH) ytmp[t] = yv[t] + dt*kk1[t];
        __syncthreads();
      }
    }

    if (t < HH){
      float ynew = yv[t] + 0.5f*dt*(kk1[t] + kk2[t]);
      yv[t] = ynew;
      out[((size_t)b*(SS+1) + (n+1))*HH + t] = ynew;
    }
    __syncthreads();
  }

  if (t < HH){
    y_state[b*HH + t] = yv[t];
    if (s1 == SS) out[OUT2_OFF + (size_t)b*HH + t] = yv[t];
  }
}

extern "C" void kernel_launch(void* const* d_in, const int* in_sizes, int n_in,
                              void* d_out, int out_size, void* d_ws, size_t ws_size,
                              hipStream_t stream)
{
  (void)in_sizes; (void)n_in; (void)out_size;
  const float* times   = (const float*)d_in[0];
  const float* logsig  = (const float*)d_in[1];
  const float* initial = (const float*)d_in[2];
  const float* in_w    = (const float*)d_in[3];
  const float* in_b    = (const float*)d_in[4];
  const float* h1_w    = (const float*)d_in[5];
  const float* h1_b    = (const float*)d_in[6];
  const float* h2_w    = (const float*)d_in[7];
  const float* h2_b    = (const float*)d_in[8];
  const float* vo_w    = (const float*)d_in[9];
  const float* vo_b    = (const float*)d_in[10];
  const float* ml_w    = (const float*)d_in[11];
  const float* ml_b    = (const float*)d_in[12];
  float* out = (float*)d_out;

  char* ws = (char*)d_ws;
  size_t off = 0;
  bf16* cA      = (bf16*)(ws + off); off += (size_t)8192*KP*2;        // 2.62 MB
  bf16* btt     = (bf16*)(ws + off); off += (size_t)NCR*KP*2;         // 10.53 MB
  uint2* w1q    = (uint2*)(ws + off); off += (size_t)32*256*8;        // 64 KB
  uint2* w2q    = (uint2*)(ws + off); off += (size_t)64*256*8;        // 128 KB
  uint2* w3q    = (uint2*)(ws + off); off += (size_t)64*256*8;        // 128 KB
  float* y_state= (float*)(ws + off); off += (size_t)BB*HH*4;         // 64 KB
  bf16* As      = (bf16*)(ws + off);
  size_t perA = (size_t)BB*NCR*2;                                     // 8.42 MB per a-index
  size_t avail = (ws_size > off) ? (ws_size - off) : 0;
  int C = (int)(avail / perA);
  if (C > SS) C = SS;
  if (C < 2) return;

  prep_coeff<<<8192, 160, 0, stream>>>(logsig, cA);
  prep_btt<<<NCR, 160, 0, stream>>>(ml_w, ml_b, btt);
  prep_wpack<<<160, 256, 0, stream>>>(h1_w, h2_w, vo_w, w1q, w2q, w3q);

  int s = 0, aB = 0;
  while (s < SS){
    int cc = SS - aB; if (cc > C) cc = C;
    agemm_kernel<<<dim3(cc*2, 257), 256, 0, stream>>>(cA, btt, As, aB*BB);
    int sEnd = aB + cc; if (sEnd > SS) sEnd = SS;
    scan_kernel<<<BB, 1024, 0, stream>>>(times, initial, in_w, in_b,
        h1_b, h2_b, vo_b, w1q, w2q, w3q, As, y_state, out, s, sEnd, aB);
    s = sEnd;
    aB = sEnd - 1;
  }
}